// Round 1
// baseline (102.416 us; speedup 1.0000x reference)
//
#include <hip/hip_runtime.h>

// DependencyGenerator: out[b][i][j] = 1.0, then scatter dep_emb[dep_type] at
// (dep_i, dep_j) per batch row; last duplicate index wins (numpy semantics).
// b=128, L=512 (seq_len scalar input is redundant; L hardcoded, b derived).

#define SEQ_L   512
#define LM1     511               // entries per row
#define ROWELEM (SEQ_L * SEQ_L)   // 262144 floats per row
#define BPR     8                 // blocks per row
#define CHUNK   (ROWELEM / BPR)   // 32768 floats per block
#define NT      256               // threads per block

__global__ __launch_bounds__(NT) void depmask_kernel(
    const int*   __restrict__ dep_i,
    const int*   __restrict__ dep_j,
    const int*   __restrict__ dep_type,
    const float* __restrict__ dep_emb,
    float*       __restrict__ out)
{
    __shared__ int   s_idx[LM1];
    __shared__ float s_val[LM1];

    const int row   = blockIdx.x / BPR;
    const int chunk = blockIdx.x % BPR;
    const int t     = threadIdx.x;

    // Stage this row's scatter entries (indices + gathered embedding values).
    const int base = row * LM1;
    for (int k = t; k < LM1; k += NT) {
        const int i  = dep_i[base + k];
        const int j  = dep_j[base + k];
        const int ty = dep_type[base + k];
        s_idx[k] = i * SEQ_L + j;
        s_val[k] = dep_emb[ty];     // 53-entry table, L1-resident
    }

    // Fill this block's chunk with 1.0 (float4 = 16 B/lane, coalesced).
    float* rowout = out + (size_t)row * ROWELEM + (size_t)chunk * CHUNK;
    float4* o4 = reinterpret_cast<float4*>(rowout);
    const float4 ones = make_float4(1.f, 1.f, 1.f, 1.f);
    #pragma unroll
    for (int v = 0; v < CHUNK / 4 / NT; ++v) {
        o4[(size_t)v * NT + t] = ones;
    }

    // Barrier drains vmcnt(0): fill stores complete before scatter stores.
    __syncthreads();

    // Scatter entries falling in this chunk; last duplicate index wins.
    const int lo = chunk * CHUNK, hi = lo + CHUNK;
    for (int k = t; k < LM1; k += NT) {
        const int idx = s_idx[k];
        if (idx >= lo && idx < hi) {
            bool last = true;
            for (int k2 = k + 1; k2 < LM1; ++k2) {
                if (s_idx[k2] == idx) { last = false; break; }
            }
            if (last) out[(size_t)row * ROWELEM + idx] = s_val[k];
        }
    }
}

extern "C" void kernel_launch(void* const* d_in, const int* in_sizes, int n_in,
                              void* d_out, int out_size, void* d_ws, size_t ws_size,
                              hipStream_t stream) {
    const int*   dep_i    = (const int*)  d_in[0];
    const int*   dep_j    = (const int*)  d_in[1];
    const int*   dep_type = (const int*)  d_in[2];
    // d_in[3] = seq_len scalar (512) -- compile-time constant here
    const float* dep_emb  = (const float*)d_in[4];
    float*       out      = (float*)      d_out;

    const int b = in_sizes[0] / LM1;   // 128
    depmask_kernel<<<dim3(b * BPR), dim3(NT), 0, stream>>>(
        dep_i, dep_j, dep_type, dep_emb, out);
}